// Round 1
// baseline (942.327 us; speedup 1.0000x reference)
//
#include <hip/hip_runtime.h>

typedef unsigned int u32;
typedef unsigned short u16;

#define NEG 0.01f
#define BN_EPS 1e-5f

typedef __attribute__((ext_vector_type(8))) short bf16x8;
typedef __attribute__((ext_vector_type(4))) float f32x4;

__device__ __forceinline__ float bl(u32 u){ union { u32 i; float f; } c; c.i = u << 16; return c.f; }
__device__ __forceinline__ float bh(u32 u){ union { u32 i; float f; } c; c.i = u & 0xFFFF0000u; return c.f; }
__device__ __forceinline__ float b2f(u16 u){ union { u32 i; float f; } c; c.i = ((u32)u) << 16; return c.f; }
__device__ __forceinline__ u16 f2b(float f){
  union { float f; u32 i; } c; c.f = f;
  u32 t = c.i + 0x7FFFu + ((c.i >> 16) & 1u);
  return (u16)(t >> 16);
}
__device__ __forceinline__ float leaky(float v){ return v > 0.f ? v : NEG * v; }

// ---------------------------------------------------------------------------
// Kernel 0: weight prep (fp32 -> bf16 tables in ws).
//  [0,49152)          : desW16[64][768]
//  [49152,57344)      : Wmlp[64][128]  row h: {rgcnW0[h][0..63], rgcnW1[h][0..63]}
//  [57344,59392)      : W1p[32][64]    cls_W1 rows
// ---------------------------------------------------------------------------
__global__ void k_prep(const float* __restrict__ desWf, const float* __restrict__ rgcnW,
                       const float* __restrict__ W1, u16* __restrict__ tab)
{
  int i = blockIdx.x * 256 + threadIdx.x;
  if (i < 49152) {
    tab[i] = f2b(desWf[i]);
  } else if (i < 57344) {
    int j = i - 49152;            // h*128 + k
    int h = j >> 7, k = j & 127;
    tab[i] = f2b(rgcnW[(k >= 64 ? 4096 : 0) + h * 64 + (k & 63)]);
  } else if (i < 59392) {
    tab[i] = f2b(W1[i - 57344]);
  }
}

// ---------------------------------------------------------------------------
// Kernel 1: fusion GEMM via MFMA (fp32 inputs) -> x16[node][64] bf16.
// ---------------------------------------------------------------------------
__global__ __launch_bounds__(256) void k_fuse(
    const float* __restrict__ des, const float* __restrict__ nump, const float* __restrict__ catp,
    const u16* __restrict__ desW16, const float* __restrict__ desB,
    const float* __restrict__ numW, const float* __restrict__ numB,
    const float* __restrict__ catW, const float* __restrict__ catB,
    const float* __restrict__ dg, const float* __restrict__ dbe, const float* __restrict__ dm, const float* __restrict__ dv,
    const float* __restrict__ ng, const float* __restrict__ nbe, const float* __restrict__ nm, const float* __restrict__ nv,
    const float* __restrict__ cg, const float* __restrict__ cbe, const float* __restrict__ cm, const float* __restrict__ cv,
    u16* __restrict__ x16, int n)
{
  __shared__ float ync[64][66];

  const int tid  = threadIdx.x;
  const int lane = tid & 63;
  const int w    = tid >> 6;
  const int quad = lane >> 4;
  const int l15  = lane & 15;
  const int rowbase = blockIdx.x * 64 + 16 * w;

  {
    float nw[5], cw[6];
    #pragma unroll
    for (int j = 0; j < 5; ++j) nw[j] = numW[lane * 5 + j];
    #pragma unroll
    for (int j = 0; j < 6; ++j) cw[j] = catW[lane * 6 + j];
    float An = ng[lane] * rsqrtf(nv[lane] + BN_EPS);
    float Bn = (numB[lane] - nm[lane]) * An + nbe[lane];
    float Ac = cg[lane] * rsqrtf(cv[lane] + BN_EPS);
    float Bc = (catB[lane] - cm[lane]) * Ac + cbe[lane];
    for (int m = 0; m < 16; ++m) {
      int node = rowbase + m; if (node > n - 1) node = n - 1;
      float yn = 0.f, yc = 0.f;
      #pragma unroll
      for (int j = 0; j < 5; ++j) yn = fmaf(nump[node * 5 + j], nw[j], yn);
      #pragma unroll
      for (int j = 0; j < 6; ++j) yc = fmaf(catp[node * 6 + j], cw[j], yc);
      ync[16 * w + m][lane] = leaky(yn * An + Bn) + leaky(yc * Ac + Bc);
    }
  }

  float Ad4[4], Bd4[4];
  #pragma unroll
  for (int t = 0; t < 4; ++t) {
    int nn = 16 * t + l15;
    float A = dg[nn] * rsqrtf(dv[nn] + BN_EPS);
    Ad4[t] = A;
    Bd4[t] = (desB[nn] - dm[nn]) * A + dbe[nn];
  }
  __syncthreads();

  int rowA = rowbase + l15; if (rowA > n - 1) rowA = n - 1;
  const float* aP  = des + (size_t)rowA * 768 + quad * 8;
  const u16* b0P = desW16 + (size_t)(l15)      * 768 + quad * 8;
  const u16* b1P = desW16 + (size_t)(16 + l15) * 768 + quad * 8;
  const u16* b2P = desW16 + (size_t)(32 + l15) * 768 + quad * 8;
  const u16* b3P = desW16 + (size_t)(48 + l15) * 768 + quad * 8;

  f32x4 acc[4];
  #pragma unroll
  for (int t = 0; t < 4; ++t) acc[t] = (f32x4){0.f, 0.f, 0.f, 0.f};

  #pragma unroll 2
  for (int k = 0; k < 768; k += 32) {
    float4 x0 = *(const float4*)(aP + k);
    float4 x1 = *(const float4*)(aP + k + 4);
    bf16x8 a;
    a[0] = (short)f2b(x0.x); a[1] = (short)f2b(x0.y);
    a[2] = (short)f2b(x0.z); a[3] = (short)f2b(x0.w);
    a[4] = (short)f2b(x1.x); a[5] = (short)f2b(x1.y);
    a[6] = (short)f2b(x1.z); a[7] = (short)f2b(x1.w);
    acc[0] = __builtin_amdgcn_mfma_f32_16x16x32_bf16(a, *(const bf16x8*)(b0P + k), acc[0], 0, 0, 0);
    acc[1] = __builtin_amdgcn_mfma_f32_16x16x32_bf16(a, *(const bf16x8*)(b1P + k), acc[1], 0, 0, 0);
    acc[2] = __builtin_amdgcn_mfma_f32_16x16x32_bf16(a, *(const bf16x8*)(b2P + k), acc[2], 0, 0, 0);
    acc[3] = __builtin_amdgcn_mfma_f32_16x16x32_bf16(a, *(const bf16x8*)(b3P + k), acc[3], 0, 0, 0);
  }

  #pragma unroll
  for (int t = 0; t < 4; ++t) {
    #pragma unroll
    for (int r = 0; r < 4; ++r) {
      int m = quad * 4 + r;
      int node = rowbase + m;
      if (node < n) {
        int nn = 16 * t + l15;
        float v = leaky(acc[t][r] * Ad4[t] + Bd4[t]) + ync[16 * w + m][nn];
        x16[(size_t)node * 64 + nn] = f2b(v);
      }
    }
  }
}

// ---------------------------------------------------------------------------
// Kernel 2: per-(dst,rel) histogram. bin = dst*2 + rel
// ---------------------------------------------------------------------------
__global__ void k_hist(const int* __restrict__ ei, const int* __restrict__ et,
                       int E, int* __restrict__ deg2)
{
  int e = blockIdx.x * 256 + threadIdx.x;
  if (e < E) atomicAdd(&deg2[ei[E + e] * 2 + et[e]], 1);
}

// ---------------------------------------------------------------------------
// Kernel 3: exclusive prefix sum over M=2N bins (single block, x4 vectorized)
// ---------------------------------------------------------------------------
__global__ __launch_bounds__(1024) void k_scan(const int* __restrict__ deg2, int* __restrict__ offs2, int M)
{
  __shared__ int wsum[16];
  __shared__ int carry;
  const int tid = threadIdx.x, lane = tid & 63, w = tid >> 6;
  if (tid == 0) carry = 0;
  __syncthreads();
  for (int base = 0; base < M; base += 4096) {
    int idx = base + tid * 4;
    int4 v = {0, 0, 0, 0};
    if (idx < M) v = *(const int4*)(deg2 + idx);
    int s4 = v.x + v.y + v.z + v.w;
    int s = s4;
    #pragma unroll
    for (int o = 1; o < 64; o <<= 1) { int t = __shfl_up(s, o); if (lane >= o) s += t; }
    if (lane == 63) wsum[w] = s;
    __syncthreads();
    if (w == 0 && lane < 16) {
      int t = wsum[lane];
      #pragma unroll
      for (int o = 1; o < 16; o <<= 1) { int u = __shfl_up(t, o); if (lane >= o) t += u; }
      wsum[lane] = t;
    }
    __syncthreads();
    int wbase = (w == 0) ? 0 : wsum[w - 1];
    int ebase = carry + wbase + (s - s4);
    if (idx < M) {
      int4 o4;
      o4.x = ebase;
      o4.y = ebase + v.x;
      o4.z = ebase + v.x + v.y;
      o4.w = ebase + v.x + v.y + v.z;
      *(int4*)(offs2 + idx) = o4;
    }
    __syncthreads();
    if (tid == 0) carry += wsum[15];
    __syncthreads();
  }
  if (tid == 0) offs2[M] = carry;
}

// ---------------------------------------------------------------------------
// Kernel 4: CSR placement sorted by (dst, rel). packed[pos] = src
// ---------------------------------------------------------------------------
__global__ void k_place(const int* __restrict__ ei, const int* __restrict__ et, int E,
                        const int* __restrict__ offs2, int* __restrict__ cur2, int* __restrict__ packed)
{
  int e = blockIdx.x * 256 + threadIdx.x;
  if (e < E) {
    int bin = ei[E + e] * 2 + et[e];
    int pos = offs2[bin] + atomicAdd(&cur2[bin], 1);
    packed[pos] = ei[e];
  }
}

// ---------------------------------------------------------------------------
// Kernel 5: pure gather/mean. Wave per node; lane = channel-pair (c=lane&31),
// half-wave = edge substream -> one u32 wave-load gathers TWO edges' rows.
// Writes agg[node][64] u32 words (= 128 bf16: [rel0 ch0..63, rel1 ch0..63]).
// ---------------------------------------------------------------------------
__global__ __launch_bounds__(256) void k_agg(
    const u16* __restrict__ x16, const int* __restrict__ offs2, const int* __restrict__ packed,
    u32* __restrict__ agg, int n)
{
  const int tid = threadIdx.x, lane = tid & 63, w = tid >> 6;
  const int c = lane & 31, half = lane >> 5;

  for (int nd = blockIdx.x * 4 + w; nd < n; nd += gridDim.x * 4) {
    int o0 = offs2[nd * 2], o1 = offs2[nd * 2 + 1], o2 = offs2[nd * 2 + 2];
    float aE[2], aO[2];

    #pragma unroll
    for (int rel = 0; rel < 2; ++rel) {
      int beg = rel ? o1 : o0;
      int end = rel ? o2 : o1;
      float accE = 0.f, accO = 0.f;
      for (int j0 = beg; j0 < end; j0 += 64) {
        int idx = j0 + lane;
        int p = (idx < end) ? packed[idx] : 0;
        p = (p < 0) ? 0 : ((p > n - 1) ? (n - 1) : p);
        int cn = end - j0; if (cn > 64) cn = 64;
        int t = 0;
        for (; t + 8 <= cn; t += 8) {          // 8 edges: 4 dual-edge loads in flight
          int s0 = __shfl(p, t     + half);
          int s1 = __shfl(p, t + 2 + half);
          int s2 = __shfl(p, t + 4 + half);
          int s3 = __shfl(p, t + 6 + half);
          u32 v0 = *(const u32*)(x16 + (size_t)s0 * 64 + 2 * c);
          u32 v1 = *(const u32*)(x16 + (size_t)s1 * 64 + 2 * c);
          u32 v2 = *(const u32*)(x16 + (size_t)s2 * 64 + 2 * c);
          u32 v3 = *(const u32*)(x16 + (size_t)s3 * 64 + 2 * c);
          accE += (bl(v0) + bl(v1)) + (bl(v2) + bl(v3));
          accO += (bh(v0) + bh(v1)) + (bh(v2) + bh(v3));
        }
        for (; t + 2 <= cn; t += 2) {          // 2 edges per load
          int s0 = __shfl(p, t + half);
          u32 v0 = *(const u32*)(x16 + (size_t)s0 * 64 + 2 * c);
          accE += bl(v0); accO += bh(v0);
        }
        if (t < cn) {                           // odd remainder: half 0 only
          int s0 = __shfl(p, t);
          if (half == 0) {
            u32 v0 = *(const u32*)(x16 + (size_t)s0 * 64 + 2 * c);
            accE += bl(v0); accO += bh(v0);
          }
        }
      }
      accE += __shfl_xor(accE, 32);
      accO += __shfl_xor(accO, 32);
      int cnt = end - beg;
      float sc = 1.f / (float)(cnt > 1 ? cnt : 1);
      aE[rel] = accE * sc;
      aO[rel] = accO * sc;
    }

    float sE = half ? aE[1] : aE[0];
    float sO = half ? aO[1] : aO[0];
    agg[(size_t)nd * 64 + lane] = (u32)f2b(sE) | ((u32)f2b(sO) << 16);
  }
}

// ---------------------------------------------------------------------------
// Kernel 6: batched MFMA MLP.  A = agg[node][128] bf16.
// y64 = leaky(0.5 * A @ Wmlp^T); h32 = leaky(y64 @ W1p^T + b1);
// out2 = h32 @ W2^T + b2.   64 nodes/block (4 waves x 16).
// ---------------------------------------------------------------------------
__global__ __launch_bounds__(256) void k_mlp(
    const u32* __restrict__ agg, const u16* __restrict__ Wmlp, const u16* __restrict__ W1p,
    const float* __restrict__ b1, const float* __restrict__ W2, const float* __restrict__ b2,
    float2* __restrict__ out, int n)
{
  __shared__ __align__(16) u16 h1[4][16][72];   // [wave][node m][ch 0..63], 16B-aligned rows
  __shared__ float h2[4][16][34];               // [wave][node m][j 0..31]

  const int tid = threadIdx.x, lane = tid & 63, w = tid >> 6;
  const int quad = lane >> 4, l15 = lane & 15;
  const int rowbase = blockIdx.x * 64 + 16 * w;

  int rowA = rowbase + l15; if (rowA > n - 1) rowA = n - 1;
  const u16* aRow = (const u16*)(agg + (size_t)rowA * 64);   // 128 bf16

  // ---- GEMM1: [16 nodes x 128] @ [128 -> 64] ----
  f32x4 acc[4];
  #pragma unroll
  for (int t = 0; t < 4; ++t) acc[t] = (f32x4){0.f, 0.f, 0.f, 0.f};
  #pragma unroll
  for (int ks = 0; ks < 4; ++ks) {
    bf16x8 a = *(const bf16x8*)(aRow + ks * 32 + quad * 8);
    #pragma unroll
    for (int t = 0; t < 4; ++t) {
      bf16x8 b = *(const bf16x8*)(Wmlp + (size_t)(16 * t + l15) * 128 + ks * 32 + quad * 8);
      acc[t] = __builtin_amdgcn_mfma_f32_16x16x32_bf16(a, b, acc[t], 0, 0, 0);
    }
  }
  #pragma unroll
  for (int t = 0; t < 4; ++t)
    #pragma unroll
    for (int r = 0; r < 4; ++r) {
      int m = quad * 4 + r;
      h1[w][m][16 * t + l15] = f2b(leaky(0.5f * acc[t][r]));
    }
  __syncthreads();

  // ---- GEMM2: [16 x 64] @ [64 -> 32] ----
  f32x4 acc2[2];
  acc2[0] = (f32x4){0.f, 0.f, 0.f, 0.f};
  acc2[1] = (f32x4){0.f, 0.f, 0.f, 0.f};
  #pragma unroll
  for (int ks = 0; ks < 2; ++ks) {
    bf16x8 a = *(const bf16x8*)(&h1[w][l15][ks * 32 + quad * 8]);
    #pragma unroll
    for (int t = 0; t < 2; ++t) {
      bf16x8 b = *(const bf16x8*)(W1p + (size_t)(16 * t + l15) * 64 + ks * 32 + quad * 8);
      acc2[t] = __builtin_amdgcn_mfma_f32_16x16x32_bf16(a, b, acc2[t], 0, 0, 0);
    }
  }
  #pragma unroll
  for (int t = 0; t < 2; ++t)
    #pragma unroll
    for (int r = 0; r < 4; ++r) {
      int m = quad * 4 + r;
      int j = 16 * t + l15;
      h2[w][m][j] = leaky(acc2[t][r] + b1[j]);
    }
  __syncthreads();

  // ---- final 32 -> 2: lane (quad,l15): node l15, j-range quad*8..+8 ----
  float t0 = 0.f, t1 = 0.f;
  #pragma unroll
  for (int jj = 0; jj < 8; ++jj) {
    int j = quad * 8 + jj;
    float hv = h2[w][l15][j];
    t0 = fmaf(hv, W2[j], t0);
    t1 = fmaf(hv, W2[32 + j], t1);
  }
  t0 += __shfl_xor(t0, 16); t0 += __shfl_xor(t0, 32);
  t1 += __shfl_xor(t1, 16); t1 += __shfl_xor(t1, 32);
  int node = rowbase + l15;
  if (quad == 0 && node < n) {
    float2 q; q.x = t0 + b2[0]; q.y = t1 + b2[1];
    out[node] = q;
  }
}

// ---------------------------------------------------------------------------
extern "C" void kernel_launch(void* const* d_in, const int* in_sizes, int n_in,
                              void* d_out, int out_size, void* d_ws, size_t ws_size,
                              hipStream_t stream)
{
  const float* des  = (const float*)d_in[0];
  const float* nump = (const float*)d_in[1];
  const float* catp = (const float*)d_in[2];
  const int* ei   = (const int*)d_in[3];
  const int* et   = (const int*)d_in[4];
  const float* desW = (const float*)d_in[5];
  const float* desB = (const float*)d_in[6];
  const float* numW = (const float*)d_in[7];
  const float* numB = (const float*)d_in[8];
  const float* catW = (const float*)d_in[9];
  const float* catB = (const float*)d_in[10];
  const float* dg  = (const float*)d_in[11];
  const float* dbe = (const float*)d_in[12];
  const float* dm  = (const float*)d_in[13];
  const float* dv  = (const float*)d_in[14];
  const float* ng  = (const float*)d_in[15];
  const float* nbe = (const float*)d_in[16];
  const float* nm  = (const float*)d_in[17];
  const float* nv  = (const float*)d_in[18];
  const float* cg  = (const float*)d_in[19];
  const float* cbe = (const float*)d_in[20];
  const float* cm  = (const float*)d_in[21];
  const float* cv  = (const float*)d_in[22];
  const float* rgcnW = (const float*)d_in[23];
  const float* W1 = (const float*)d_in[24];
  const float* b1 = (const float*)d_in[25];
  const float* W2 = (const float*)d_in[26];
  const float* b2 = (const float*)d_in[27];

  const int N = in_sizes[1] / 5;   // num is (N,5)
  const int E = in_sizes[4];       // edge_type is (E,)
  const int M = 2 * N;             // (dst, rel) bins

  // workspace layout
  char* ws = (char*)d_ws;
  u16* tab    = (u16*)ws;                  size_t off = (size_t)59392 * 2;      // weight tables
  off = (off + 255) & ~(size_t)255;
  u16* x16    = (u16*)(ws + off);          off += (size_t)N * 64 * 2;
  u32* agg    = (u32*)(ws + off);          off += (size_t)N * 64 * 4;
  int* deg2   = (int*)(ws + off);          off += (size_t)M * 4;
  int* cur2   = (int*)(ws + off);          off += (size_t)M * 4;
  int* offs2  = (int*)(ws + off);          off += (size_t)(M + 1) * 4;
  off = (off + 255) & ~(size_t)255;
  int* packed = (int*)(ws + off);

  u16* desW16 = tab;
  u16* Wmlp   = tab + 49152;
  u16* W1p    = tab + 57344;

  hipMemsetAsync(deg2, 0, (size_t)M * 8, stream);     // zero deg2 + cur2 (adjacent)
  // NOTE: packed memset removed — k_place writes every slot of packed[0,E)
  // exactly once (bin cursors partition [0,E)), and k_agg only reads idx<end.

  k_prep<<<(59392 + 255) / 256, 256, 0, stream>>>(desW, rgcnW, W1, tab);
  k_fuse<<<(N + 63) / 64, 256, 0, stream>>>(des, nump, catp, desW16, desB, numW, numB, catW, catB,
                                            dg, dbe, dm, dv, ng, nbe, nm, nv, cg, cbe, cm, cv,
                                            x16, N);
  k_hist<<<(E + 255) / 256, 256, 0, stream>>>(ei, et, E, deg2);
  k_scan<<<1, 1024, 0, stream>>>(deg2, offs2, M);
  k_place<<<(E + 255) / 256, 256, 0, stream>>>(ei, et, E, offs2, cur2, packed);
  k_agg<<<2048, 256, 0, stream>>>(x16, offs2, packed, agg, N);
  k_mlp<<<(N + 63) / 64, 256, 0, stream>>>(agg, Wmlp, W1p, b1, W2, b2, (float2*)d_out, N);
}